// Round 1
// baseline (140.421 us; speedup 1.0000x reference)
//
#include <hip/hip_runtime.h>

typedef _Float16 half8 __attribute__((ext_vector_type(8)));
typedef _Float16 half4 __attribute__((ext_vector_type(4)));
typedef float floatx4 __attribute__((ext_vector_type(4)));

#define IN_DIM 256
#define OUT_DIM 256
#define M_TILE 64
#define ROWSTR 264  // 256 + 8 f16 pad (stride%32 banks = 4 -> bank-uniform ds_read_b128)

// Fused kernel: quantizes W (rne(w*100) -> f16) on the fly from the float weights
// (L2-resident, 256KB) instead of a separate quant kernel + 128KB global round-trip.
// Per block: 64 batch rows x 256 out cols. A = W (quantized in-register),
// B = c_x (staged int32->f16 via LDS). D: row(quad*4+reg)=out col, col(lane&15)=batch row
// -> float4 stores of 4 consecutive out cols per lane.
__global__ __launch_bounds__(256, 4) void gemm_fused(const int* __restrict__ cx,
                                                     const float* __restrict__ w,
                                                     const float* __restrict__ bias,
                                                     const float* __restrict__ in_scale,
                                                     float* __restrict__ out,
                                                     float* __restrict__ out_scalar) {
    __shared__ _Float16 cT[M_TILE * ROWSTR];

    const int t = threadIdx.x;
    const size_t m0 = (size_t)blockIdx.x * M_TILE;

    const float s2 = in_scale[0] * 100.0f;   // uniform scalar load, overlaps staging

    // ---- stage 64 rows x 256 int32 -> f16, coalesced int4 loads ----
    const int* cbase = cx + m0 * IN_DIM;
#pragma unroll
    for (int i = 0; i < 16; ++i) {
        int flat = i * 1024 + t * 4;
        int4 v = *(const int4*)(cbase + flat);
        int row = flat >> 8;
        int col = flat & 255;
        half4 h;
        h.x = (_Float16)v.x; h.y = (_Float16)v.y;
        h.z = (_Float16)v.z; h.w = (_Float16)v.w;
        *(half4*)&cT[row * ROWSTR + col] = h;
    }
    __syncthreads();

    const int wave = t >> 6;
    const int lane = t & 63;
    const int m16  = lane & 15;
    const int quad = lane >> 4;

    floatx4 acc[4][4] = {};   // [i: out-col tile][j: batch-row tile]

    // A-frag source: row = wave*64 + i*16 + m16, k = ks*32 + quad*8 + e
    const float* wl = w + (size_t)(wave * 64 + m16) * IN_DIM + quad * 8;

#pragma unroll
    for (int ks = 0; ks < 8; ++ks) {
        half8 bfrg[4];
        const int kb = ks * 32 + quad * 8;
#pragma unroll
        for (int j = 0; j < 4; ++j)          // ds_read_b128, bank-uniform
            bfrg[j] = *(const half8*)&cT[(j * 16 + m16) * ROWSTR + kb];
#pragma unroll
        for (int i = 0; i < 4; ++i) {
            const float* src = wl + i * 16 * IN_DIM + ks * 32;
            floatx4 w0 = *(const floatx4*)src;        // L2-hit after warmup
            floatx4 w1 = *(const floatx4*)(src + 4);
            half8 af;
#pragma unroll
            for (int e = 0; e < 4; ++e) {
                af[e]     = (_Float16)rintf(w0[e] * 100.0f);  // jnp.round = rne; exact ints <2048 in f16
                af[e + 4] = (_Float16)rintf(w1[e] * 100.0f);
            }
#pragma unroll
            for (int j = 0; j < 4; ++j)
                acc[i][j] = __builtin_amdgcn_mfma_f32_16x16x32_f16(af, bfrg[j], acc[i][j], 0, 0, 0);
        }
    }

    // ---- epilogue: lane owns 4 consecutive out cols -> float4 stores ----
#pragma unroll
    for (int i = 0; i < 4; ++i) {
        int col = wave * 64 + i * 16 + quad * 4;
        floatx4 bv = *(const floatx4*)(bias + col);
        floatx4 bq;
#pragma unroll
        for (int e = 0; e < 4; ++e)
            bq[e] = rintf(bv[e] * s2);       // quantized bias, exact int in f32
#pragma unroll
        for (int j = 0; j < 4; ++j) {
            size_t row = m0 + j * 16 + m16;
            floatx4 v = acc[i][j] + bq;
            *(floatx4*)(out + row * OUT_DIM + col) = v;
        }
    }

    if (out_scalar != nullptr && blockIdx.x == 0 && t == 0)
        out_scalar[0] = s2;
}

extern "C" void kernel_launch(void* const* d_in, const int* in_sizes, int n_in,
                              void* d_out, int out_size, void* d_ws, size_t ws_size,
                              hipStream_t stream) {
    const int*   cx       = (const int*)d_in[0];
    const float* w        = (const float*)d_in[1];
    const float* bias     = (const float*)d_in[2];
    const float* in_scale = (const float*)d_in[3];
    float* out = (float*)d_out;

    const int rows = in_sizes[0] / IN_DIM;          // 65536
    const size_t gemm_elems = (size_t)rows * OUT_DIM;
    float* out_scalar = ((size_t)out_size > gemm_elems) ? (out + gemm_elems) : nullptr;

    gemm_fused<<<rows / M_TILE, 256, 0, stream>>>(cx, w, bias, in_scale, out, out_scalar);
}